// Round 1
// baseline (237.681 us; speedup 1.0000x reference)
//
#include <hip/hip_runtime.h>
#include <math.h>

// Gaussian blur 21x21, sigma=5, depthwise over [B=32, C=3, H=512, W=512] fp32,
// reflect padding (mirror, no edge repeat), separable.
//
// Fused single-kernel design: per-block 64x64 output tile.
//   1) load (64+20)^2 = 84x84 input tile w/ reflect halo -> LDS (28.2 KB)
//   2) horizontal 21-tap -> 84x64 LDS buffer (21.5 KB)
//   3) vertical 21-tap -> registers -> coalesced global store
// LDS total 49.7 KB -> 3 blocks/CU. Grid 8x8x96 = 6144 blocks (24/CU).

#define KS   21
#define PAD  10
#define TILE 64
#define LW   (TILE + 2 * PAD)   // 84
#define IMG_H 512
#define IMG_W 512
#define NTHREADS 256

__global__ __launch_bounds__(NTHREADS) void gauss_blur_kernel(
    const float* __restrict__ in, float* __restrict__ out)
{
    __shared__ float s_in[LW * LW];    // 84*84 = 7056 floats
    __shared__ float s_h[LW * TILE];   // 84*64 = 5376 floats

    // Normalized 1-D Gaussian weights (sum of outer(g,g) = sum(g)^2, so
    // normalizing the 1-D kernel reproduces the reference's 2-D normalization).
    float w[KS];
    {
        float s = 0.f;
#pragma unroll
        for (int k = 0; k < KS; ++k) {
            float d = (float)(k - PAD);
            w[k] = expf(-d * d * (1.0f / 50.0f));  // 2*sigma^2 = 50
            s += w[k];
        }
        float inv = 1.0f / s;
#pragma unroll
        for (int k = 0; k < KS; ++k) w[k] *= inv;
    }

    const int tid   = threadIdx.x;
    const int plane = blockIdx.z;                 // b*C + c, 0..95
    const int x0    = blockIdx.x * TILE;
    const int y0    = blockIdx.y * TILE;

    const float* __restrict__ pin = in + (size_t)plane * (IMG_H * IMG_W);

    // ---- stage 1: global -> LDS with reflect indexing ----
    for (int idx = tid; idx < LW * LW; idx += NTHREADS) {
        int ly = idx / LW;
        int lx = idx - ly * LW;
        int gy = y0 + ly - PAD;
        int gx = x0 + lx - PAD;
        gy = (gy < 0) ? -gy : ((gy >= IMG_H) ? (2 * IMG_H - 2 - gy) : gy);
        gx = (gx < 0) ? -gx : ((gx >= IMG_W) ? (2 * IMG_W - 2 - gx) : gx);
        s_in[idx] = pin[gy * IMG_W + gx];
    }
    __syncthreads();

    // ---- stage 2: horizontal 21-tap, rows 0..83, output cols 0..63 ----
    for (int idx = tid; idx < LW * TILE; idx += NTHREADS) {
        int ly = idx >> 6;        // /64
        int lx = idx & 63;        // %64
        const float* row = &s_in[ly * LW + lx];
        float acc = 0.f;
#pragma unroll
        for (int k = 0; k < KS; ++k) acc += w[k] * row[k];
        s_h[idx] = acc;
    }
    __syncthreads();

    // ---- stage 3: vertical 21-tap + store ----
    float* __restrict__ pout = out + (size_t)plane * (IMG_H * IMG_W);
    for (int idx = tid; idx < TILE * TILE; idx += NTHREADS) {
        int oy = idx >> 6;
        int ox = idx & 63;
        const float* col = &s_h[oy * TILE + ox];
        float acc = 0.f;
#pragma unroll
        for (int k = 0; k < KS; ++k) acc += w[k] * col[k * TILE];
        pout[(size_t)(y0 + oy) * IMG_W + (x0 + ox)] = acc;
    }
}

extern "C" void kernel_launch(void* const* d_in, const int* in_sizes, int n_in,
                              void* d_out, int out_size, void* d_ws, size_t ws_size,
                              hipStream_t stream)
{
    const float* x = (const float*)d_in[0];
    float* out = (float*)d_out;

    // 32 batches * 3 channels = 96 planes, 8x8 tiles of 64x64 per plane
    dim3 grid(IMG_W / TILE, IMG_H / TILE, 96);
    dim3 block(NTHREADS);
    gauss_blur_kernel<<<grid, block, 0, stream>>>(x, out);
}

// Round 2
// 229.498 us; speedup vs baseline: 1.0357x; 1.0357x over previous
//
#include <hip/hip_runtime.h>
#include <math.h>

// Gaussian blur 21x21, sigma=5, depthwise over [B=32, C=3, H=512, W=512] fp32,
// reflect padding, separable, fused single kernel.
//
// R2: register-blocked stages with ds_read_b128.
//   stage2: each thread -> 4 consecutive x outputs (6 float4 LDS loads, 84 FMA)
//   stage3: each thread -> 4x4 output block (24 float4 LDS loads, 336 FMA)
// LDS wave-instruction count drops ~13x vs R1 (21 scalar reads/output -> 1.5).

#define KS   21
#define PAD  10
#define TILE 64
#define LW   (TILE + 2 * PAD)   // 84
#define IMG_H 512
#define IMG_W 512
#define NTHREADS 256

__global__ __launch_bounds__(NTHREADS) void gauss_blur_kernel(
    const float* __restrict__ in, float* __restrict__ out)
{
    __shared__ __align__(16) float s_in[LW * LW];    // 84*84 floats = 28.2 KB
    __shared__ __align__(16) float s_h[LW * TILE];   // 84*64 floats = 21.5 KB

    // Normalized 1-D Gaussian (sum(outer(g,g)) = sum(g)^2, so 1-D normalization
    // reproduces the reference's 2-D normalization).
    float w[KS];
    {
        float s = 0.f;
#pragma unroll
        for (int k = 0; k < KS; ++k) {
            float d = (float)(k - PAD);
            w[k] = expf(-d * d * (1.0f / 50.0f));  // 2*sigma^2 = 50
            s += w[k];
        }
        float inv = 1.0f / s;
#pragma unroll
        for (int k = 0; k < KS; ++k) w[k] *= inv;
    }

    const int tid   = threadIdx.x;
    const int plane = blockIdx.z;                 // b*C + c, 0..95
    const int x0    = blockIdx.x * TILE;
    const int y0    = blockIdx.y * TILE;

    const float* __restrict__ pin = in + (size_t)plane * (IMG_H * IMG_W);

    // ---- stage 1: global -> LDS with reflect indexing ----
    for (int idx = tid; idx < LW * LW; idx += NTHREADS) {
        int ly = idx / LW;
        int lx = idx - ly * LW;
        int gy = y0 + ly - PAD;
        int gx = x0 + lx - PAD;
        gy = (gy < 0) ? -gy : ((gy >= IMG_H) ? (2 * IMG_H - 2 - gy) : gy);
        gx = (gx < 0) ? -gx : ((gx >= IMG_W) ? (2 * IMG_W - 2 - gx) : gx);
        s_in[idx] = pin[gy * IMG_W + gx];
    }
    __syncthreads();

    // ---- stage 2: horizontal 21-tap, 4 outputs/thread ----
    // items: 84 rows x 16 col-groups = 1344
    for (int idx = tid; idx < LW * (TILE / 4); idx += NTHREADS) {
        int ly = idx >> 4;            // row 0..83
        int lx = (idx & 15) << 2;     // col 0,4,...,60
        const float4* rp = (const float4*)&s_in[ly * LW + lx];  // LW%4==0, lx%4==0 -> aligned
        float v[24];
#pragma unroll
        for (int t = 0; t < 6; ++t) {
            float4 f = rp[t];
            v[4 * t + 0] = f.x; v[4 * t + 1] = f.y;
            v[4 * t + 2] = f.z; v[4 * t + 3] = f.w;
        }
        float a0 = 0.f, a1 = 0.f, a2 = 0.f, a3 = 0.f;
#pragma unroll
        for (int k = 0; k < KS; ++k) {
            float wk = w[k];
            a0 += wk * v[k + 0];
            a1 += wk * v[k + 1];
            a2 += wk * v[k + 2];
            a3 += wk * v[k + 3];
        }
        *(float4*)&s_h[ly * TILE + lx] = make_float4(a0, a1, a2, a3);
    }
    __syncthreads();

    // ---- stage 3: vertical 21-tap, 4x4 block/thread (exactly 1 iter) ----
    {
        const int rg = tid >> 4;          // 0..15
        const int cg = tid & 15;          // 0..15
        const int oy = rg << 2;
        const int ox = cg << 2;

        float4 r0 = make_float4(0, 0, 0, 0);
        float4 r1 = make_float4(0, 0, 0, 0);
        float4 r2 = make_float4(0, 0, 0, 0);
        float4 r3 = make_float4(0, 0, 0, 0);

        // accumulate-on-load: row t contributes to output row j with tap k=t-j
#pragma unroll
        for (int t = 0; t < KS + 3; ++t) {           // 24 rows
            float4 c = *(const float4*)&s_h[(oy + t) * TILE + ox];
            if (t - 0 >= 0 && t - 0 < KS) { float wk = w[t - 0]; r0.x += wk * c.x; r0.y += wk * c.y; r0.z += wk * c.z; r0.w += wk * c.w; }
            if (t - 1 >= 0 && t - 1 < KS) { float wk = w[t - 1]; r1.x += wk * c.x; r1.y += wk * c.y; r1.z += wk * c.z; r1.w += wk * c.w; }
            if (t - 2 >= 0 && t - 2 < KS) { float wk = w[t - 2]; r2.x += wk * c.x; r2.y += wk * c.y; r2.z += wk * c.z; r2.w += wk * c.w; }
            if (t - 3 >= 0 && t - 3 < KS) { float wk = w[t - 3]; r3.x += wk * c.x; r3.y += wk * c.y; r3.z += wk * c.z; r3.w += wk * c.w; }
        }

        float* __restrict__ pout = out + (size_t)plane * (IMG_H * IMG_W)
                                       + (size_t)(y0 + oy) * IMG_W + (x0 + ox);
        *(float4*)&pout[0 * IMG_W] = r0;
        *(float4*)&pout[1 * IMG_W] = r1;
        *(float4*)&pout[2 * IMG_W] = r2;
        *(float4*)&pout[3 * IMG_W] = r3;
    }
}

extern "C" void kernel_launch(void* const* d_in, const int* in_sizes, int n_in,
                              void* d_out, int out_size, void* d_ws, size_t ws_size,
                              hipStream_t stream)
{
    const float* x = (const float*)d_in[0];
    float* out = (float*)d_out;

    dim3 grid(IMG_W / TILE, IMG_H / TILE, 96);   // 8 x 8 x (32*3) planes
    dim3 block(NTHREADS);
    gauss_blur_kernel<<<grid, block, 0, stream>>>(x, out);
}